// Round 1
// baseline (2845.457 us; speedup 1.0000x reference)
//
#include <hip/hip_runtime.h>
#include <math.h>

#ifndef M_PI
#define M_PI 3.14159265358979323846
#endif

#define B_DIM 8
#define S_DIM 8
#define T_DIM 4096
#define CIN   128
#define COUT  256
#define KT    9
#define NK    5

// ---------------- kernel 1: W_eff[s][dt][ci][co] = sum_k wt[s][dt][k] * coeffs[k][ci][co]
struct WtArgs { float wt[S_DIM * KT * NK]; };   // 360 floats = 1440 B kernarg

__global__ __launch_bounds__(256) void weights_kernel(
    const float* __restrict__ coeffs, float* __restrict__ weff, WtArgs args)
{
    int idx = blockIdx.x * 256 + threadIdx.x;           // over 8*9*128*64 = 589824 (4 co each)
    if (idx >= S_DIM * KT * CIN * (COUT / 4)) return;
    int co4 = (idx & 63) * 4;
    int ci  = (idx >> 6) & 127;
    int sdt = idx >> 13;                                // 0..71
    const float* wt = &args.wt[sdt * NK];
    float4 acc = make_float4(0.f, 0.f, 0.f, 0.f);
#pragma unroll
    for (int k = 0; k < NK; ++k) {
        float4 c = *(const float4*)&coeffs[((size_t)k * CIN + ci) * COUT + co4];
        float w = wt[k];
        acc.x += w * c.x; acc.y += w * c.y; acc.z += w * c.z; acc.w += w * c.w;
    }
    *(float4*)&weff[(size_t)idx * 4] = acc;
}

// ---------------- kernel 2: fused scale-conv + time-conv GEMM
// block tile: 64 t x 64 co; 256 threads; 4x4 outputs/thread
#define BT 64
#define BCO 64
#define AROWS 72            // BT + KT - 1
#define APITCH 132          // pad: ty-stride = 528 words = 16 mod 32 banks -> 2-way (free)

struct BsArgs { float bs[9]; };   // 3x3 scale basis (constant)

__global__ __launch_bounds__(256) void conv_kernel(
    const float* __restrict__ x, const float* __restrict__ weff,
    const float* __restrict__ cscale, float* __restrict__ out, BsArgs args)
{
    __shared__ float As[AROWS * APITCH];   // xs window, [row][ci]
    __shared__ float Bs[CIN * BCO];        // W_eff slice, [ci][col]

    const int tid = threadIdx.x;
    const int tx = tid & 15, ty = tid >> 4;
    const int t0  = blockIdx.x * BT;
    const int co0 = blockIdx.y * BCO;
    const int bsix = blockIdx.z;           // b*8 + s
    const int b = bsix >> 3, s = bsix & 7;
    const int sm = (s > 0) ? s - 1 : 0;
    const int sp = (s < 7) ? s + 1 : 7;

    // w_scale = basis_s @ coeffs_scale (coeffs_scale is device data)
    const float c0 = cscale[0], c1 = cscale[1], c2 = cscale[2];
    const float w0 = args.bs[0]*c0 + args.bs[1]*c1 + args.bs[2]*c2;
    const float w1 = args.bs[3]*c0 + args.bs[4]*c1 + args.bs[5]*c2;
    const float w2 = args.bs[6]*c0 + args.bs[7]*c1 + args.bs[8]*c2;

    const float* x0 = x + (size_t)(b * S_DIM + sm) * T_DIM * CIN;
    const float* x1 = x + (size_t)(b * S_DIM + s ) * T_DIM * CIN;
    const float* x2 = x + (size_t)(b * S_DIM + sp) * T_DIM * CIN;

    // stage xs window: rows t0-4 .. t0+67 (zero outside [0,T)), fused 3-tap scale conv
    for (int idx = tid; idx < AROWS * CIN; idx += 256) {
        int row = idx >> 7;
        int ci  = idx & 127;
        int tt = t0 - 4 + row;
        float v = 0.f;
        if (tt >= 0 && tt < T_DIM) {
            size_t off = (size_t)tt * CIN + ci;
            v = w0 * x0[off] + w1 * x1[off] + w2 * x2[off];
        }
        As[row * APITCH + ci] = v;
    }

    float acc[4][4];
#pragma unroll
    for (int i = 0; i < 4; ++i) {
        acc[i][0] = 0.f; acc[i][1] = 0.f; acc[i][2] = 0.f; acc[i][3] = 0.f;
    }

    const int ty4 = ty * 4, tx4 = tx * 4;
    const float* wbase = weff + ((size_t)s * KT * CIN) * COUT + co0;

    for (int dt = 0; dt < KT; ++dt) {
        __syncthreads();                    // protect Bs (and As on first iter)
        const float* wdt = wbase + (size_t)dt * CIN * COUT;
        for (int idx = tid; idx < CIN * BCO; idx += 256) {
            int ci  = idx >> 6;
            int col = idx & 63;
            Bs[idx] = wdt[(size_t)ci * COUT + col];
        }
        __syncthreads();
        const int rbase = ty4 + dt;         // out row r reads window row r+dt
#pragma unroll 4
        for (int ci0 = 0; ci0 < CIN; ci0 += 4) {
            float4 av[4], bv[4];
#pragma unroll
            for (int i = 0; i < 4; ++i)
                av[i] = *(const float4*)(As + (rbase + i) * APITCH + ci0);
#pragma unroll
            for (int kk = 0; kk < 4; ++kk)
                bv[kk] = *(const float4*)(Bs + (ci0 + kk) * BCO + tx4);
#pragma unroll
            for (int i = 0; i < 4; ++i) {
                const float a0 = av[i].x, a1 = av[i].y, a2 = av[i].z, a3 = av[i].w;
                acc[i][0] += a0*bv[0].x + a1*bv[1].x + a2*bv[2].x + a3*bv[3].x;
                acc[i][1] += a0*bv[0].y + a1*bv[1].y + a2*bv[2].y + a3*bv[3].y;
                acc[i][2] += a0*bv[0].z + a1*bv[1].z + a2*bv[2].z + a3*bv[3].z;
                acc[i][3] += a0*bv[0].w + a1*bv[1].w + a2*bv[2].w + a3*bv[3].w;
            }
        }
    }

    float* obase = out + ((size_t)bsix * T_DIM + t0) * COUT + co0;
#pragma unroll
    for (int i = 0; i < 4; ++i) {
        float4 v = make_float4(acc[i][0], acc[i][1], acc[i][2], acc[i][3]);
        *(float4*)(obase + (size_t)(ty4 + i) * COUT + tx4) = v;
    }
}

// ---------------- host
extern "C" void kernel_launch(void* const* d_in, const int* in_sizes, int n_in,
                              void* d_out, int out_size, void* d_ws, size_t ws_size,
                              hipStream_t stream)
{
    const float* x      = (const float*)d_in[0];   // (8,8,4096,128) fp32
    const float* coeffs = (const float*)d_in[1];   // (5,128,256) fp32
    const float* cscale = (const float*)d_in[2];   // (3,) fp32
    float* out  = (float*)d_out;                   // (8,8,4096,256) fp32
    float* weff = (float*)d_ws;                    // 8*9*128*256 fp32 = 9.4 MB

    // host-side constant tables (no device data needed)
    static const double SC[8] = {-1.5, -1.0, -0.5, 0.0, 0.5, 1.0, 1.5, 2.0};
    WtArgs wargs;
    for (int i = 0; i < S_DIM; ++i) {
        double alpha = SC[i];
        double scale = pow(2.0, alpha);
        double us    = pow(2.0, -alpha);
        for (int j = 0; j < KT; ++j) {
            double t = (j - 4.0) / 4.0;
            double u = t * us;
            double mask = (fabs(u) <= 1.0) ? 1.0 : 0.0;
            for (int k = 0; k < NK; ++k) {
                int freq = (k + 1) / 2;                 // ceil(k/2): 0,1,1,2,2
                double arg = M_PI * (double)freq * u;
                double v = (k % 2 == 0) ? cos(arg) : sin(arg);
                wargs.wt[(i * KT + j) * NK + k] = (float)(mask * v * scale);
            }
        }
    }
    BsArgs bargs;
    for (int j = 0; j < 3; ++j) {
        double t = (double)(j - 1);                     // u = t (alpha=0), |u|<=1 always
        for (int k = 0; k < 3; ++k) {
            int freq = (k + 1) / 2;
            double arg = M_PI * (double)freq * t;
            bargs.bs[j * 3 + k] = (float)((k % 2 == 0) ? cos(arg) : sin(arg));
        }
    }

    weights_kernel<<<dim3((S_DIM*KT*CIN*(COUT/4) + 255) / 256), dim3(256), 0, stream>>>(
        coeffs, weff, wargs);
    conv_kernel<<<dim3(T_DIM / BT, COUT / BCO, B_DIM * S_DIM), dim3(256), 0, stream>>>(
        x, weff, cscale, out, bargs);
}

// Round 2
// 633.073 us; speedup vs baseline: 4.4947x; 4.4947x over previous
//
#include <hip/hip_runtime.h>
#include <math.h>

#ifndef M_PI
#define M_PI 3.14159265358979323846
#endif

#define B_DIM 8
#define S_DIM 8
#define T_DIM 4096
#define CIN   128
#define COUT  256
#define KT    9
#define NK    5

typedef __attribute__((ext_vector_type(8))) short bf16x8;   // 8 bf16 = 4 VGPRs
typedef __attribute__((ext_vector_type(4))) float f32x4;    // MFMA accum

__device__ __forceinline__ unsigned short f2bf(float f) {
    union { float f; unsigned u; } v; v.f = f;
    unsigned u = v.u;
    u += 0x7fffu + ((u >> 16) & 1u);        // RNE to bf16
    return (unsigned short)(u >> 16);
}

// ---------------- kernel 1: weff_bf16[s][dt][co][ci] = bf16( sum_k wt[s,dt,k] * coeffs[k][ci][co] )
// Transposed ([co][ci]) so B-fragments are contiguous in k=ci for ds_read_b128.
struct WtArgs { float wt[S_DIM * KT * NK]; };   // 360 floats

__global__ __launch_bounds__(256) void weights_kernel(
    const float* __restrict__ coeffs, unsigned short* __restrict__ weff, WtArgs args)
{
    const int sdt = blockIdx.x;            // 0..71  (s*9+dt)
    const int ci0 = blockIdx.y * 32;       // 4 ci-chunks
    const int co  = threadIdx.x;           // 0..255
    float w[NK];
#pragma unroll
    for (int k = 0; k < NK; ++k) w[k] = args.wt[sdt * NK + k];

    for (int cc = 0; cc < 32; cc += 8) {
        uint4 pack;
        unsigned short* p = (unsigned short*)&pack;
#pragma unroll
        for (int e = 0; e < 8; ++e) {
            int ci = ci0 + cc + e;
            float acc = 0.f;
#pragma unroll
            for (int k = 0; k < NK; ++k)
                acc += w[k] * coeffs[((size_t)k * CIN + ci) * COUT + co];
            p[e] = f2bf(acc);
        }
        *(uint4*)&weff[((size_t)sdt * COUT + co) * CIN + ci0 + cc] = pack;
    }
}

// ---------------- kernel 2: fused scale-conv + bf16 MFMA time-conv GEMM
// block tile: 128 t x 128 co; 4 waves, each wave = 64x64 quadrant = 4x4 mfma_16x16x32 tiles
#define BM 128
#define BN 128
#define AROWS 136          // BM + KT - 1
#define PITCH 136          // 272 B rows: 16B-aligned, 2-way bank aliasing (free)

struct BsArgs { float bs[9]; };   // 3x3 scale basis (constant)

__global__ __launch_bounds__(256, 2) void conv_kernel(
    const float* __restrict__ x, const unsigned short* __restrict__ weff,
    const float* __restrict__ cscale, float* __restrict__ out, BsArgs args)
{
    __shared__ unsigned short As[AROWS * PITCH];   // xs window [row][ci], bf16
    __shared__ unsigned short Bs[BN * PITCH];      // W_eff slice [co][ci], bf16

    const int tid = threadIdx.x;
    const int lane = tid & 63, wave = tid >> 6;
    const int lrow = lane & 15, quad = lane >> 4;
    const int wr = (wave >> 1) * 64;               // wave row quadrant
    const int wc = (wave & 1) * 64;                // wave col quadrant

    const int t0      = blockIdx.x * BM;
    const int co_base = blockIdx.y * BN;
    const int bsix    = blockIdx.z;                // b*8 + s
    const int b = bsix >> 3, s = bsix & 7;
    const int sm = (s > 0) ? s - 1 : 0;
    const int sp = (s < 7) ? s + 1 : 7;

    // w_scale = basis @ coeffs_scale (coeffs_scale is device data)
    const float c0 = cscale[0], c1 = cscale[1], c2 = cscale[2];
    const float w0 = args.bs[0]*c0 + args.bs[1]*c1 + args.bs[2]*c2;
    const float w1 = args.bs[3]*c0 + args.bs[4]*c1 + args.bs[5]*c2;
    const float w2 = args.bs[6]*c0 + args.bs[7]*c1 + args.bs[8]*c2;

    const float* x0 = x + (size_t)(b * S_DIM + sm) * T_DIM * CIN;
    const float* x1 = x + (size_t)(b * S_DIM + s ) * T_DIM * CIN;
    const float* x2 = x + (size_t)(b * S_DIM + sp) * T_DIM * CIN;

    // ---- stage A window once: rows t0-4 .. t0+131, fused 3-tap scale conv, fp32->bf16
    for (int idx = tid; idx < AROWS * 32; idx += 256) {
        int row = idx >> 5;
        int c4  = (idx & 31) << 2;
        int tt  = t0 - 4 + row;
        ushort4 v = make_ushort4(0, 0, 0, 0);
        if (tt >= 0 && tt < T_DIM) {
            size_t off = (size_t)tt * CIN + c4;
            float4 a = *(const float4*)(x0 + off);
            float4 bb = *(const float4*)(x1 + off);
            float4 c = *(const float4*)(x2 + off);
            v.x = f2bf(w0*a.x + w1*bb.x + w2*c.x);
            v.y = f2bf(w0*a.y + w1*bb.y + w2*c.y);
            v.z = f2bf(w0*a.z + w1*bb.z + w2*c.z);
            v.w = f2bf(w0*a.w + w1*bb.w + w2*c.w);
        }
        *(ushort4*)&As[row * PITCH + c4] = v;
    }

    f32x4 acc[4][4];
#pragma unroll
    for (int i = 0; i < 4; ++i)
#pragma unroll
        for (int j = 0; j < 4; ++j)
            acc[i][j] = (f32x4){0.f, 0.f, 0.f, 0.f};

    for (int dt = 0; dt < KT; ++dt) {
        __syncthreads();                            // protect Bs reuse (and As 1st iter)
        const unsigned short* wdt =
            weff + (((size_t)(s * KT + dt)) * COUT + co_base) * CIN;
        for (int idx = tid; idx < BN * 16; idx += 256) {
            int row = idx >> 4;
            int c8  = (idx & 15) << 3;
            uint4 v = *(const uint4*)(wdt + (size_t)row * CIN + c8);
            *(uint4*)&Bs[row * PITCH + c8] = v;
        }
        __syncthreads();

#pragma unroll
        for (int ci0 = 0; ci0 < CIN; ci0 += 32) {
            bf16x8 a[4], bfr[4];
#pragma unroll
            for (int i = 0; i < 4; ++i)
                a[i] = *(const bf16x8*)&As[(wr + 16*i + lrow + dt) * PITCH + ci0 + quad*8];
#pragma unroll
            for (int j = 0; j < 4; ++j)
                bfr[j] = *(const bf16x8*)&Bs[(wc + 16*j + lrow) * PITCH + ci0 + quad*8];
#pragma unroll
            for (int i = 0; i < 4; ++i)
#pragma unroll
                for (int j = 0; j < 4; ++j)
                    acc[i][j] = __builtin_amdgcn_mfma_f32_16x16x32_bf16(
                        a[i], bfr[j], acc[i][j], 0, 0, 0);
        }
    }

    // ---- epilogue: C/D layout col=lane&15, row=quad*4+v
    float* obase = out + ((size_t)bsix * T_DIM + t0) * COUT + co_base;
#pragma unroll
    for (int i = 0; i < 4; ++i) {
#pragma unroll
        for (int j = 0; j < 4; ++j) {
            int r0 = wr + 16*i + quad*4;
            int c  = wc + 16*j + lrow;
#pragma unroll
            for (int v = 0; v < 4; ++v)
                obase[(size_t)(r0 + v) * COUT + c] = acc[i][j][v];
        }
    }
}

// ---------------- host
extern "C" void kernel_launch(void* const* d_in, const int* in_sizes, int n_in,
                              void* d_out, int out_size, void* d_ws, size_t ws_size,
                              hipStream_t stream)
{
    const float* x      = (const float*)d_in[0];   // (8,8,4096,128) fp32
    const float* coeffs = (const float*)d_in[1];   // (5,128,256) fp32
    const float* cscale = (const float*)d_in[2];   // (3,) fp32
    float* out = (float*)d_out;                    // (8,8,4096,256) fp32
    unsigned short* weff = (unsigned short*)d_ws;  // bf16 [s][dt][co][ci] = 4.7 MB

    static const double SC[8] = {-1.5, -1.0, -0.5, 0.0, 0.5, 1.0, 1.5, 2.0};
    WtArgs wargs;
    for (int i = 0; i < S_DIM; ++i) {
        double alpha = SC[i];
        double scale = pow(2.0, alpha);
        double us    = pow(2.0, -alpha);
        for (int j = 0; j < KT; ++j) {
            double t = (j - 4.0) / 4.0;
            double u = t * us;
            double mask = (fabs(u) <= 1.0) ? 1.0 : 0.0;
            for (int k = 0; k < NK; ++k) {
                int freq = (k + 1) / 2;
                double arg = M_PI * (double)freq * u;
                double v = (k % 2 == 0) ? cos(arg) : sin(arg);
                wargs.wt[(i * KT + j) * NK + k] = (float)(mask * v * scale);
            }
        }
    }
    BsArgs bargs;
    for (int j = 0; j < 3; ++j) {
        double t = (double)(j - 1);
        for (int k = 0; k < 3; ++k) {
            int freq = (k + 1) / 2;
            double arg = M_PI * (double)freq * t;
            bargs.bs[j * 3 + k] = (float)((k % 2 == 0) ? cos(arg) : sin(arg));
        }
    }

    weights_kernel<<<dim3(S_DIM * KT, 4), dim3(256), 0, stream>>>(coeffs, weff, wargs);
    conv_kernel<<<dim3(T_DIM / BM, COUT / BN, B_DIM * S_DIM), dim3(256), 0, stream>>>(
        x, weff, cscale, out, bargs);
}